// Round 1
// baseline (130.194 us; speedup 1.0000x reference)
//
#include <hip/hip_runtime.h>
#include <stdint.h>

// Problem constants
#define NB   16      // batch
#define NC   128
#define NT   8
#define NBR  16
#define NS   8
#define NSY  64
#define NIN  16384   // = NC*NT*NBR = INPUT_SIZE

// ---------------------------------------------------------------------------
// Kernel A: pack x (B x NIN float 0/1) into per-position 16-bit batch masks.
// xpack[i] bit b = (x[b][i] != 0)
// ---------------------------------------------------------------------------
__global__ __launch_bounds__(256) void k_pack(const float* __restrict__ x,
                                              uint16_t* __restrict__ xpack) {
    const int i = blockIdx.x * 256 + threadIdx.x;   // grid = 64*256 = NIN exactly
    uint32_t m = 0;
#pragma unroll
    for (int b = 0; b < NB; ++b)
        m |= (x[b * NIN + i] != 0.0f) ? (1u << b) : 0u;
    xpack[i] = (uint16_t)m;
}

// ---------------------------------------------------------------------------
// Shared layer body: one wave computes one branch's 16-batch output mask.
// lane = synapse index (SY == 64 == wave width). Per segment:
//   - coalesced 256B idx load (one dword/lane)
//   - LDS gather of 16-bit batch mask
//   - 16 ballots -> per-batch counts over the 64 synapses
// ---------------------------------------------------------------------------
__device__ __forceinline__ uint32_t branch_mask(const uint16_t* lds,
                                                const int* __restrict__ ip /* +lane */) {
    int bs[NB];
#pragma unroll
    for (int b = 0; b < NB; ++b) bs[b] = 0;
#pragma unroll
    for (int s = 0; s < NS; ++s) {
        const int iv = ip[s * NSY];
        uint32_t m = (uint32_t)lds[iv & (NIN - 1)];
        m &= ~(uint32_t)(iv >> 31);          // zero mask when iv == -1
#pragma unroll
        for (int b = 0; b < NB; ++b) {
            const unsigned long long bal = __ballot(m & (1u << b));
            bs[b] += (__popcll(bal) >= 16) ? 1 : 0;   // SEG_TH
        }
    }
    uint32_t om = 0;
#pragma unroll
    for (int b = 0; b < NB; ++b)
        om |= (bs[b] >= 4) ? (1u << b) : 0u;          // BR_TH
    return om;
}

// ---------------------------------------------------------------------------
// Kernel B: layer 1 over all NIN branches. 16 branches/block (4 per wave).
// grid = 1024 blocks x 256 threads. LDS-stages xpack (32 KB).
// ---------------------------------------------------------------------------
__global__ __launch_bounds__(256) void k_layer1(const uint16_t* __restrict__ xpack,
                                                const int* __restrict__ idx1,
                                                uint16_t* __restrict__ act1pack) {
    __shared__ __align__(16) uint16_t lds[NIN];   // 32 KB
    {
        const uint4* s = (const uint4*)xpack;
        uint4* d = (uint4*)lds;
#pragma unroll
        for (int k = 0; k < 8; ++k)
            d[k * 256 + threadIdx.x] = s[k * 256 + threadIdx.x];
    }
    __syncthreads();

    const int lane = threadIdx.x & 63;
    const int wave = threadIdx.x >> 6;
    for (int k = 0; k < 4; ++k) {
        const int bidx = blockIdx.x * 16 + wave * 4 + k;          // [0, NIN)
        const int* ip = idx1 + bidx * (NS * NSY) + lane;
        const uint32_t om = branch_mask(lds, ip);
        if (lane == 0) act1pack[bidx] = (uint16_t)om;
    }
}

// ---------------------------------------------------------------------------
// Kernel C: layer 2, t = 0 only (NC*NBR = 2048 branches). 8 branches/block
// (2 per wave). grid = 256 blocks x 256 threads. LDS-stages act1pack.
// Output: out[b*2048 + j] = bit b of branch j's mask (int32 0/1).
// ---------------------------------------------------------------------------
__global__ __launch_bounds__(256) void k_layer2(const uint16_t* __restrict__ act1pack,
                                                const int* __restrict__ idx2,
                                                int* __restrict__ out) {
    __shared__ __align__(16) uint16_t lds[NIN];   // 32 KB
    {
        const uint4* s = (const uint4*)act1pack;
        uint4* d = (uint4*)lds;
#pragma unroll
        for (int k = 0; k < 8; ++k)
            d[k * 256 + threadIdx.x] = s[k * 256 + threadIdx.x];
    }
    __syncthreads();

    const int lane = threadIdx.x & 63;
    const int wave = threadIdx.x >> 6;
    for (int k = 0; k < 2; ++k) {
        const int j = blockIdx.x * 8 + wave * 2 + k;              // [0, 2048)
        const int c = j >> 4;
        const int br = j & 15;
        // branch (c, t=0, br): offset = ((c*NT + 0)*NBR + br) * NS*NSY
        const int* ip = idx2 + (c * (NT * NBR) + br) * (NS * NSY) + lane;
        const uint32_t om = branch_mask(lds, ip);
        if (lane < NB) out[lane * (NC * NBR) + j] = (int)((om >> lane) & 1u);
    }
}

// ---------------------------------------------------------------------------
extern "C" void kernel_launch(void* const* d_in, const int* in_sizes, int n_in,
                              void* d_out, int out_size, void* d_ws, size_t ws_size,
                              hipStream_t stream) {
    const float* x    = (const float*)d_in[0];
    const int*   idx1 = (const int*)d_in[1];
    const int*   idx2 = (const int*)d_in[2];

    uint16_t* xpack    = (uint16_t*)d_ws;                       // 32 KB
    uint16_t* act1pack = (uint16_t*)((char*)d_ws + 32768);      // 32 KB
    int*      out      = (int*)d_out;

    k_pack  <<<NIN / 256, 256, 0, stream>>>(x, xpack);
    k_layer1<<<NIN / 16,  256, 0, stream>>>(xpack, idx1, act1pack);
    k_layer2<<<(NC * NBR) / 8, 256, 0, stream>>>(act1pack, idx2, out);
}